// Round 12
// baseline (157.960 us; speedup 1.0000x reference)
//
#include <hip/hip_runtime.h>
#include <math.h>

#define KM 16
#define KS 64
#define TWO_PI_F 6.283185307179586477f

// Workspace float-offset layout:
//   [0..64]      sxk (65)   [65..129] syk   [130..194] sdk
//   [195..258]   sknot (64) sorted outer knots
//   [8709..12868]   SROOT: 65 intervals * 64 sorted sub-roots
//   [12872..418471] COEF: 4225 regions * 96 floats (48 (a,b) pairs)
#define WS_SXK   0
#define WS_SYK   65
#define WS_SDK   130
#define WS_KNOT  195
#define WS_SROOT 8709
#define WS_COEF  12872
#define WS_NEED  (12872 + 4225 * 96)

__device__ __forceinline__ float frcp(float x) { return __builtin_amdgcn_rcpf(x); }

// 4-quadrant atan2, max err ~1e-5 rad (tolerance 3.1e-2).
__device__ __forceinline__ float fast_atan2(float y, float x) {
    const float ax = fabsf(x), ay = fabsf(y);
    const float mx = fmaxf(ax, ay), mn = fminf(ax, ay);
    const float t = mn * frcp(mx);
    const float s = t * t;
    float p = -0.01172120f;
    p = fmaf(p, s,  0.05265332f);
    p = fmaf(p, s, -0.11643287f);
    p = fmaf(p, s,  0.19354346f);
    p = fmaf(p, s, -0.33262347f);
    p = fmaf(p, s,  0.99997726f);
    p = p * t;
    p = (ay > ax) ? (1.57079632679f - p) : p;
    p = (x < 0.0f) ? (3.14159265359f - p) : p;
    p = (y < 0.0f) ? -p : p;
    return p;
}

// ===========================================================================
// Precompute for one interval v — VERBATIM the R9/R11-verified device function
// (absmax 0.03125). R7 serial coefficient order.
// ===========================================================================
__device__ __forceinline__ void precompute_interval(
    int v, int tid,
    const float* __restrict__ theta_w, const float* __restrict__ theta_h,
    const float* __restrict__ theta_d,
    const float* __restrict__ W1, const float* __restrict__ b1,
    const float* __restrict__ W2, const float* __restrict__ b2,
    const float* __restrict__ W3, const float* __restrict__ b3,
    float* __restrict__ ws,
    float* p_tjs, float* p_sAv, float* p_sBv, float* p_sknotS, float* p_rroot,
    int* p_srnk, int* p_jinv)
{
    if (tid < 64) {
        const float w1 = W1[tid], bb = b1[tid];
        p_tjs[tid] = (w1 != 0.0f) ? (-bb / w1) : INFINITY;
    }
    __syncthreads();
    if (tid < 64) {                       // distinct ranks, tie-break by index
        const float t = p_tjs[tid];
        int rk = 0;
        #pragma unroll 8
        for (int k2 = 0; k2 < 64; k2++) {
            const float tk = p_tjs[k2];
            rk += (tk < t || (tk == t && k2 < tid)) ? 1 : 0;
        }
        p_srnk[tid] = rk;
        p_sknotS[rk] = t;
    }
    __syncthreads();

    if (tid < 64) {                       // A,B for interval v
        const int i = tid;
        float cA = 0.0f, cB = b2[i];
        #pragma unroll 8
        for (int j = 0; j < 64; j++) {
            const float w1 = W1[j];            // uniform -> s_load
            const float bb = b1[j];
            const float w2 = W2[j * 64 + i];   // coalesced
            if (w1 > 0.0f) {
                if (p_srnk[j] < v)  { cA = fmaf(w1, w2, cA); cB = fmaf(bb, w2, cB); }
            } else if (w1 < 0.0f) {
                if (p_srnk[j] >= v) { cA = fmaf(w1, w2, cA); cB = fmaf(bb, w2, cB); }
            } else {
                cB = fmaf(fmaxf(bb, 0.0f), w2, cB);
            }
        }
        p_sAv[i] = cA; p_sBv[i] = cB;
    }
    __syncthreads();

    if (tid < 64)
        p_rroot[tid] = (p_sAv[tid] != 0.0f) ? (-p_sBv[tid] / p_sAv[tid]) : INFINITY;
    __syncthreads();
    if (tid < 64) {
        const float t = p_rroot[tid];
        int rk = 0;
        #pragma unroll 8
        for (int k2 = 0; k2 < 64; k2++) {
            const float tk = p_rroot[k2];
            rk += (tk < t || (tk == t && k2 < tid)) ? 1 : 0;
        }
        p_jinv[rk] = tid;
        ws[WS_SROOT + v * 64 + rk] = t;
    }
    __syncthreads();

    // coefficient rows: R7 serial incremental order. lane = o; W3 coalesced.
    if (tid < 48) {
        const int o = tid;
        float a = 0.0f, b = b3[o];
        #pragma unroll 8
        for (int j = 0; j < 64; j++) {
            const float A = p_sAv[j], B = p_sBv[j];
            const float w3 = W3[j * 48 + o];
            const bool act = (A < 0.0f) || (A == 0.0f && B > 0.0f);
            const float m = act ? w3 : 0.0f;
            a = fmaf(A, m, a);
            b = fmaf(B, m, b);
        }
        float* __restrict__ rowbase = ws + WS_COEF + (size_t)(v * 65) * 96;
        rowbase[2 * o]     = a;
        rowbase[2 * o + 1] = b;
        #pragma unroll 4
        for (int s = 1; s <= 64; s++) {
            const int js = p_jinv[s - 1];
            const float A = p_sAv[js], B = p_sBv[js];
            const float w3 = W3[js * 48 + o];
            const float sgn = (A > 0.0f) ? w3 : ((A < 0.0f) ? -w3 : 0.0f);
            a = fmaf(A, sgn, a);
            b = fmaf(B, sgn, b);
            rowbase[s * 96 + 2 * o]     = a;
            rowbase[s * 96 + 2 * o + 1] = b;
        }
    }

    if (v == 0 && tid < 64) {             // spline tables + sorted outer knots
        ws[WS_KNOT + tid] = p_sknotS[tid];

        float vw = theta_w[tid];
        float vh = theta_h[tid];
        float mw = vw, mh = vh;
        #pragma unroll
        for (int off = 32; off > 0; off >>= 1) {
            mw = fmaxf(mw, __shfl_xor(mw, off));
            mh = fmaxf(mh, __shfl_xor(mh, off));
        }
        const float ew = expf(vw - mw);
        const float eh = expf(vh - mh);
        float sumw = ew, sumh = eh;
        #pragma unroll
        for (int off = 32; off > 0; off >>= 1) {
            sumw += __shfl_xor(sumw, off);
            sumh += __shfl_xor(sumh, off);
        }
        float cw = ew / sumw * 2.0f;
        float ch = eh / sumh * 2.0f;
        #pragma unroll
        for (int off = 1; off < 64; off <<= 1) {   // inclusive shfl scan
            const float uw = __shfl_up(cw, off);
            const float uh = __shfl_up(ch, off);
            if (tid >= off) { cw += uw; ch += uh; }
        }
        ws[WS_SXK + 1 + tid] = cw - 1.0f;
        ws[WS_SYK + 1 + tid] = ch - 1.0f;
        if (tid < KS - 1) {
            const float x = theta_d[tid];
            const float sp = (x > 20.0f) ? x : log1pf(expf(x));
            ws[WS_SDK + 1 + tid] = sp + 0.001f;
        }
        if (tid == 0) {
            ws[WS_SXK] = -1.0f;
            ws[WS_SYK] = -1.0f;
            ws[WS_SDK] = 1.0f;
            ws[WS_SDK + KS] = 1.0f;
        }
    }
}

__global__ __launch_bounds__(256)
void precompute_k(const float* __restrict__ theta_w,
                  const float* __restrict__ theta_h,
                  const float* __restrict__ theta_d,
                  const float* __restrict__ W1,
                  const float* __restrict__ b1,
                  const float* __restrict__ W2,
                  const float* __restrict__ b2,
                  const float* __restrict__ W3,
                  const float* __restrict__ b3,
                  float* __restrict__ ws)
{
    __shared__ float p_tjs[64], p_sAv[64], p_sBv[64], p_sknotS[64], p_rroot[64];
    __shared__ int   p_srnk[64], p_jinv[64];
    precompute_interval(blockIdx.x, threadIdx.x,
                        theta_w, theta_h, theta_d, W1, b1, W2, b2, W3, b3,
                        ws, p_tjs, p_sAv, p_sBv, p_sknotS, p_rroot,
                        p_srnk, p_jinv);
}

// ===========================================================================
// MAIN kernel: R6-verified 1-point body, but sroots is NOT staged to LDS.
// The 16.6 KB sroots table is permanently L2/L3-resident (16.6 KB total,
// re-read by all 3907 blocks); staging it cost 16 global loads + 16 LDS
// writes per thread + a barrier on every short-lived block, and pushed LDS
// to 18.4 KB (8-block/CU cap -> ramp-limited achieved occupancy).
// Guide Common-mistake #7 (m169): stage only what doesn't cache-fit.
// Sub-region search reads ws directly: top levels are wave-convergent
// (L1 broadcast), deep levels are L2 hits hidden by higher wave residency.
// LDS now ~1 KB (spline tables + sknot, which feed 13 dependent steps).
// ===========================================================================
__global__ __launch_bounds__(256)
void mobius_spline_kernel(const float* __restrict__ r_in,
                          const float* __restrict__ z_in,
                          const float* __restrict__ ws,
                          float* __restrict__ out,
                          int n)
{
    __shared__ float sxk[KS + 1], syk[KS + 1], sdk[KS + 1];
    __shared__ float sknot[KS];

    const int tid = threadIdx.x;

    for (int t2 = tid; t2 < 65; t2 += 256) {
        sxk[t2] = ws[WS_SXK + t2];
        syk[t2] = ws[WS_SYK + t2];
        sdk[t2] = ws[WS_SDK + t2];
    }
    for (int t2 = tid; t2 < 64; t2 += 256) sknot[t2] = ws[WS_KNOT + t2];
    __syncthreads();

    const int idx = blockIdx.x * 256 + tid;
    if (idx >= n) return;

    const float rv = r_in[idx];
    const float zz = z_in[idx];

    // ---------------- spline ----------------
    int lo = 0, hi = KS + 1;
    while (lo < hi) {
        const int mid = (lo + hi) >> 1;
        if (sxk[mid] < rv) lo = mid + 1; else hi = mid;
    }
    int k = lo;
    k = (k == 0) ? 1 : k;
    k = (k == KS + 1) ? KS : k;
    k -= 1;
    const float x_k = sxk[k], x_nk = sxk[k + 1];
    const float y_k = syk[k], y_nk = syk[k + 1];
    const float d_k = sdk[k], d_nk = sdk[k + 1];
    const float rdx = frcp(x_nk - x_k);
    const float dy  = y_nk - y_k;
    const float s_k = dy * rdx;
    const float eps = (rv - x_k) * rdx;
    const float ome = 1.0f - eps;
    const float den = s_k + (d_nk + d_k - 2.0f * s_k) * eps * ome;
    const float rden = frcp(den);
    const float tr  = fmaf(dy * (s_k * eps * eps + d_k * eps * ome), rden, y_k);
    const float dtr = s_k * s_k * (d_nk * eps * eps + 2.0f * s_k * eps * ome + d_k * ome * ome)
                      * rden * rden;

    // ---------------- region lookup: outer interval v (LDS), sub-region s
    //                  (global, L2-resident table) ----------------
    int lo2 = 0, hi2 = KS;
    while (lo2 < hi2) {
        const int mid = (lo2 + hi2) >> 1;
        if (sknot[mid] < rv) lo2 = mid + 1; else hi2 = mid;
    }
    const int v = lo2;                    // 0..64
    const float* __restrict__ groots = ws + WS_SROOT + v * 64;
    int lo3 = 0, hi3 = 64;
    while (lo3 < hi3) {
        const int mid = (lo3 + hi3) >> 1;
        if (groots[mid] < rv) lo3 = mid + 1; else hi3 = mid;
    }
    const int s = lo3;                    // 0..64

    const float4* __restrict__ row4 =
        (const float4*)(ws + WS_COEF + (size_t)(v * 65 + s) * 96);

    // ---------------- theta logits: th_q = a*rv + b ----------------
    float th[16];
    #pragma unroll
    for (int o8 = 0; o8 < 8; o8++) {
        const float4 c = row4[o8];
        th[2 * o8]     = fmaf(c.x, rv, c.y);
        th[2 * o8 + 1] = fmaf(c.z, rv, c.w);
    }
    float mx = th[0];
    #pragma unroll
    for (int q = 1; q < 16; q++) mx = fmaxf(mx, th[q]);

    float cz, sz;
    __sincosf(zz, &sz, &cz);

    float wsum = 0.0f, tsum = 0.0f, dsum = 0.0f;

    #pragma unroll 4
    for (int q = 0; q < 16; q++) {
        const float4 c = row4[8 + q];     // (a_wx, b_wx, a_wy, b_wy)
        const float rwx = fmaf(c.x, rv, c.y);
        const float rwy = fmaf(c.z, rv, c.w);
        const float nrm = __builtin_amdgcn_sqrtf(rwx * rwx + rwy * rwy);
        const float scl = 0.99f * frcp(1.0f + nrm);
        const float wxx = scl * rwx, wyy = scl * rwy;
        const float wn2 = wxx * wxx + wyy * wyy;
        const float omw = 1.0f - wn2;
        const float dzx = cz - wxx, dzy = sz - wyy;
        const float dn2z = dzx * dzx + dzy * dzy;
        const float cf = omw * frcp(dn2z);
        const float hzx = cf * dzx - wxx;
        const float hzy = cf * dzy - wyy;
        const float d0x = 1.0f - wxx, d0y = -wyy;
        const float dn20 = d0x * d0x + d0y * d0y;
        const float c0 = omw * frcp(dn20);
        const float h0x = c0 * d0x - wxx;
        const float h0y = c0 * d0y - wyy;
        const float cross = hzy * h0x - hzx * h0y;
        const float dotp  = hzx * h0x + hzy * h0y;
        float tx = fast_atan2(cross, dotp);
        tx = (tx >= 0.0f) ? tx : tx + TWO_PI_F;

        const float ew = __expf(th[q] - mx);
        wsum += ew;
        tsum += ew * tx;
        dsum += ew * cf;                  // |dh| = cf exactly
    }

    const float inv = frcp(wsum);
    const float tz  = tsum * inv;
    const float dtz = dsum * inv;
    const float ldj = __logf(dtr) + __logf(dtz);

    out[idx]         = tr;
    out[n + idx]     = tz;
    out[2 * n + idx] = ldj;
}

extern "C" void kernel_launch(void* const* d_in, const int* in_sizes, int n_in,
                              void* d_out, int out_size, void* d_ws, size_t ws_size,
                              hipStream_t stream) {
    const int n = in_sizes[0];  // 1,000,000
    float* ws = (float*)d_ws;

    hipLaunchKernelGGL(precompute_k, dim3(65), dim3(256), 0, stream,
                       (const float*)d_in[2], (const float*)d_in[3],
                       (const float*)d_in[4], (const float*)d_in[5],
                       (const float*)d_in[6], (const float*)d_in[7],
                       (const float*)d_in[8], (const float*)d_in[9],
                       (const float*)d_in[10], ws);

    const int blocks = (n + 255) / 256;
    hipLaunchKernelGGL(mobius_spline_kernel, dim3(blocks), dim3(256), 0, stream,
                       (const float*)d_in[0], (const float*)d_in[1],
                       (const float*)ws, (float*)d_out, n);
}